// Round 9
// baseline (1162.373 us; speedup 1.0000x reference)
//
#include <hip/hip_runtime.h>

// CharNNClassifier: out = (LSTM(emb[x]) last h) @ W_out^T + b_out
// B=256 S=512 V=256 E=128 H=256 4H=1024 O=128, fp32 in/out.
//
// R11 = R10 at 4 waves/SIMD (occupancy attack on the ~1400 cyc of stalls).
//  (R8 bench attempt hit an infra failure - container died before pytest;
//   kernel re-audited: no spin loops, LDS 132.9K < 160K, bounds OK ->
//   resubmitted unchanged.)
//  R10 post-mortem: step 3881 cyc vs the 2484-cyc zero-exchange MFMA floor
//  (per-wg MFMA work is invariant: every wg multiplies all of W_hh).
//  Remaining gap = per-wave stalls, unhidden at 2 waves/SIMD.
//  R11: 64 wgs x 1024 threads (16 waves, 4 waves/SIMD).
//   - wave wv owns 64 gate-cols: col = j*256 + wv*16 + l15, j=0..3 -> j IS
//     the gate index. With the R10 row trick (batch row rb at A row 4*rb),
//     acc[t][0] = gate t, unit wv*16+l15, batch row quad: ONE gate-set
//     per lane, c-state one scalar. Epilogue halves again.
//   - 1024-thr blocks REQUIRE <=128 VGPR/lane: W split = kt0..1 wlds
//     (128 KB LDS), kt2..4 wreg[4][3] (48 reg), kt5..7 streamed from Wpk
//     (192 KB, L2-resident) with ping-pong 4-frag windows (32 reg live).
//     Budget ~121.
//  LDS = 128K wlds + 4.25K hbuf + 0.5K zbuf = 132.9 KB (1 block/CU).

typedef _Float16 f16x8 __attribute__((ext_vector_type(8)));
typedef _Float16 f16x4 __attribute__((ext_vector_type(4)));
typedef float    f32x4 __attribute__((ext_vector_type(4)));

#define B_  256
#define S_  512
#define V_  256
#define E_  128
#define H_  256
#define O_  128

// ws layout (bytes)
#define T_OFF     0u              // T2h: 256*256*4 fp16 = 512 KiB
#define HLAST_OFF (512u << 10)    // hlast: 256*256*4B   = 256 KiB
#define WPK_OFF   (768u << 10)    // Wpk: 12*1024*16B    = 192 KiB

// ---------------------------------------------------------------- K1: table
// T2h[v][unit] = fp16x4 {i,f,g,o} pre-activations from the embedding path.
__global__ void build_table(const float* __restrict__ emb,
                            const float* __restrict__ W_ih,
                            const float* __restrict__ b_ih,
                            const float* __restrict__ b_hh,
                            _Float16* __restrict__ T2h) {
    const int v   = blockIdx.x;   // vocab id
    const int tid = threadIdx.x;  // 256 threads = hidden unit

    __shared__ float e[E_];
    if (tid < E_) e[tid] = emb[v * E_ + tid];
    __syncthreads();

    f16x4 tv;
#pragma unroll
    for (int t = 0; t < 4; ++t) {
        const int g = t * 256 + tid;
        const float4* wp = (const float4*)(W_ih + g * E_);
        float acc = 0.f;
#pragma unroll
        for (int i = 0; i < E_ / 4; ++i) {
            float4 w = wp[i];
            acc += w.x * e[4*i] + w.y * e[4*i+1] + w.z * e[4*i+2] + w.w * e[4*i+3];
        }
        tv[t] = (_Float16)(acc + b_ih[g] + b_hh[g]);
    }
    *(f16x4*)(T2h + ((size_t)v * 256 + tid) * 4) = tv;
}

// ------------------------------------------------------- K1b: W-frag prepack
// Wpk[blk=ktS*4+j][tid] = the f16x8 B-fragment thread tid (of 1024) needs
// for (kt = 5+ktS, gate j). Lane math mirrors the main kernel.
__global__ void prepack(const float* __restrict__ W_hh,
                        _Float16* __restrict__ Wpk) {
    const int blk = blockIdx.x;      // 0..11 = ktS*4 + j
    const int ktS = blk >> 2;
    const int j   = blk & 3;
    const int kt  = 5 + ktS;
    const int tid = threadIdx.x;     // 1024
    const int wv = tid >> 6, l = tid & 63, l15 = l & 15, quad = l >> 4;
    const int n  = j * 256 + wv * 16 + l15;   // gate row of W (gate j, unit)
    const int k0 = kt * 32 + quad * 8;
    const float4* wp = (const float4*)(W_hh + (size_t)n * H_ + k0);
    float4 w0 = wp[0];
    float4 w1 = wp[1];
    f16x8 f = (f16x8){
        (_Float16)w0.x, (_Float16)w0.y, (_Float16)w0.z, (_Float16)w0.w,
        (_Float16)w1.x, (_Float16)w1.y, (_Float16)w1.z, (_Float16)w1.w};
    *(f16x8*)(Wpk + ((size_t)blk * 1024 + tid) * 8) = f;
}

// ------------------------------------------------------------ K2: recurrence
// Pre-act bounds: |W_hh row . h| <= 256*(1/16) = 16 hard; |table| < ~5.
// Sigmoid needs no clamp; tanh keeps a +-30 clamp as overflow insurance.
__device__ __forceinline__ float sig_fast(float x) {
    float t = __builtin_amdgcn_exp2f(-1.4426950408889634f * x);
    return __builtin_amdgcn_rcpf(1.f + t);
}
__device__ __forceinline__ float tanh_fast(float x) {
    x = fminf(fmaxf(x, -30.f), 30.f);
    float t = __builtin_amdgcn_exp2f(-2.8853900817779268f * x);  // e^{-2x}
    return (1.f - t) * __builtin_amdgcn_rcpf(1.f + t);
}

#define HSTRIDE 272   // fp16/row: 544 B => row bank-phase 0/8/16/24

__launch_bounds__(1024, 4)
__global__ void lstm_persistent(const int* __restrict__ x,
                                const float* __restrict__ W_hh,
                                const _Float16* __restrict__ T2h,
                                const _Float16* __restrict__ Wpk,
                                float* __restrict__ hlast) {
    const int tid    = threadIdx.x;
    const int wv     = tid >> 6;     // wave 0..15
    const int l      = tid & 63;
    const int l15    = l & 15;
    const int quad   = l >> 4;       // 0..3 == this lane's batch row (local)
    const int stripe = blockIdx.x;   // batch rows [stripe*4, +4)
    const int uu     = wv * 16 + l15;    // this lane's hidden unit (0..255)

    // LDS: 128 KB weights (kt 0..1) + 4-row h dbuf + zero block.
    __shared__ __align__(16) _Float16 wlds[16][4][2][512];  // 128 KiB
    __shared__ __align__(16) _Float16 hbuf[2][4][HSTRIDE];  // 4.25 KiB
    __shared__ __align__(16) _Float16 zbuf[256];            // 512 B zeros

    if (tid < 128) ((int*)zbuf)[tid] = 0;

    // ---- prologue: kt 0..4 of W_hh -> fp16 B-frags (kt 0..1 LDS, 2..4 reg)
    // col n = j*256 + uu; k = kt*32 + quad*8 + i; B[k][n] = W_hh[n][k].
    f16x8 wreg[4][3];
#pragma unroll
    for (int j = 0; j < 4; ++j) {
        const float* wr = W_hh + (size_t)(j * 256 + uu) * H_ + quad * 8;
#pragma unroll
        for (int kt = 0; kt < 5; ++kt) {
            const float4* wp = (const float4*)(wr + kt * 32);
            float4 w0 = wp[0];
            float4 w1 = wp[1];
            f16x8 f = (f16x8){
                (_Float16)w0.x, (_Float16)w0.y, (_Float16)w0.z, (_Float16)w0.w,
                (_Float16)w1.x, (_Float16)w1.y, (_Float16)w1.z, (_Float16)w1.w};
            if (kt < 2)
                *(f16x8*)&wlds[wv][j][kt][(size_t)l * 8] = f;
            else
                wreg[j][kt - 2] = f;
        }
    }

    const int grow = stripe * 4 + quad;   // this lane's global batch row
    float c1 = 0.f;                       // c[row=quad][unit=uu]

    // x prefetch: 1 step ahead (row quad).
    int xv = x[(size_t)grow * S_];

    __syncthreads();   // wlds + zbuf visible

    for (int s = 0; s < S_; ++s) {
        // T2h gather for THIS step (consumed in epilogue; MFMAs cover latency)
        f16x4 tcv = *(const f16x4*)(T2h + ((size_t)xv * 256 + uu) * 4);
        if (s + 1 < S_) xv = x[(size_t)grow * S_ + s + 1];

        f32x4 acc[4];
#pragma unroll
        for (int j = 0; j < 4; ++j) acc[j] = (f32x4){0.f, 0.f, 0.f, 0.f};

        if (s > 0) {
            // A row m = l15; real rows {0,4,8,12} hold batch row m/4, the
            // rest read the zero block. k = kt*32 + quad*8 + i.
            const _Float16* ha = ((l15 & 3) == 0)
                ? (&hbuf[(s - 1) & 1][l15 >> 2][0] + quad * 8)
                : (zbuf + quad * 8);

            // kt5 window issued up front (5 kts of MFMA cover).
            f16x8 wstA[4], wstB[4];
#pragma unroll
            for (int j = 0; j < 4; ++j)
                wstA[j] = *(const f16x8*)(
                    Wpk + ((size_t)((0 * 4 + j) * 1024 + tid)) * 8);

#pragma unroll
            for (int kt = 0; kt < 8; ++kt) {
                f16x8 a = *(const f16x8*)(ha + kt * 32);
                if (kt < 2) {
#pragma unroll
                    for (int j = 0; j < 4; ++j) {
                        f16x8 b = *(const f16x8*)&wlds[wv][j][kt][(size_t)l * 8];
                        acc[j] = __builtin_amdgcn_mfma_f32_16x16x32_f16(
                            a, b, acc[j], 0, 0, 0);
                    }
                } else if (kt < 5) {
#pragma unroll
                    for (int j = 0; j < 4; ++j)
                        acc[j] = __builtin_amdgcn_mfma_f32_16x16x32_f16(
                            a, wreg[j][kt - 2], acc[j], 0, 0, 0);
                } else if (kt == 5) {
#pragma unroll
                    for (int j = 0; j < 4; ++j)
                        acc[j] = __builtin_amdgcn_mfma_f32_16x16x32_f16(
                            a, wstA[j], acc[j], 0, 0, 0);
                } else if (kt == 6) {
#pragma unroll
                    for (int j = 0; j < 4; ++j)
                        acc[j] = __builtin_amdgcn_mfma_f32_16x16x32_f16(
                            a, wstB[j], acc[j], 0, 0, 0);
                } else {
#pragma unroll
                    for (int j = 0; j < 4; ++j)
                        acc[j] = __builtin_amdgcn_mfma_f32_16x16x32_f16(
                            a, wstA[j], acc[j], 0, 0, 0);
                }
                // window prefetches (ping-pong, 32 regs peak):
                if (kt == 4) {      // kt6 frags, 1 kt of cover
#pragma unroll
                    for (int j = 0; j < 4; ++j)
                        wstB[j] = *(const f16x8*)(
                            Wpk + ((size_t)((1 * 4 + j) * 1024 + tid)) * 8);
                } else if (kt == 5) {  // kt7 frags reuse wstA (WAR via HW)
#pragma unroll
                    for (int j = 0; j < 4; ++j)
                        wstA[j] = *(const f16x8*)(
                            Wpk + ((size_t)((2 * 4 + j) * 1024 + tid)) * 8);
                }
            }
        }

        // ---- epilogue straight from registers: gate t = acc[t][0]
        // (C row 4*quad = reg 0 of this lane; col = t*256 + uu).
        const bool last = (s == S_ - 1);
        {
            float gi = sig_fast (acc[0][0] + (float)tcv[0]);
            float gf = sig_fast (acc[1][0] + (float)tcv[1]);
            float gg = tanh_fast(acc[2][0] + (float)tcv[2]);
            float go = sig_fast (acc[3][0] + (float)tcv[3]);
            float cc = gf * c1 + gi * gg;
            c1 = cc;
            float hv = go * tanh_fast(cc);
            if (!last) {
                hbuf[s & 1][quad][uu] = (_Float16)hv;
            } else {
                hlast[(size_t)grow * H_ + uu] = hv;
            }
        }

        // one barrier per step: h_s (all units) visible to all A-reads at
        // s+1; buffer s&1 readers done before s+2 overwrites.
        __syncthreads();
    }
}

// ---------------------------------------------------------------- K3: head
__global__ void out_kernel(const float* __restrict__ hlast,
                           const float* __restrict__ W_out,
                           const float* __restrict__ b_out,
                           float* __restrict__ out) {
    const int b = blockIdx.x;    // 256
    const int o = threadIdx.x;   // 128
    __shared__ float hl[H_];
    hl[o]       = hlast[b * H_ + o];
    hl[o + 128] = hlast[b * H_ + o + 128];
    __syncthreads();
    const float4* wp = (const float4*)(W_out + o * H_);
    float acc = 0.f;
#pragma unroll
    for (int i = 0; i < H_ / 4; ++i) {
        float4 w = wp[i];
        acc += w.x * hl[4*i] + w.y * hl[4*i+1] + w.z * hl[4*i+2] + w.w * hl[4*i+3];
    }
    out[b * O_ + o] = acc + b_out[o];
}

// ----------------------------------------------------------------- launcher
extern "C" void kernel_launch(void* const* d_in, const int* in_sizes, int n_in,
                              void* d_out, int out_size, void* d_ws, size_t ws_size,
                              hipStream_t stream) {
    const int*   x     = (const int*)  d_in[0];
    const float* emb   = (const float*)d_in[1];
    const float* W_ih  = (const float*)d_in[2];
    const float* W_hh  = (const float*)d_in[3];
    const float* b_ih  = (const float*)d_in[4];
    const float* b_hh  = (const float*)d_in[5];
    const float* W_out = (const float*)d_in[6];
    const float* b_out = (const float*)d_in[7];
    float* out = (float*)d_out;

    char* ws = (char*)d_ws;
    _Float16* T2h   = (_Float16*)(ws + T_OFF);
    float*    hlast = (float*)(ws + HLAST_OFF);
    _Float16* Wpk   = (_Float16*)(ws + WPK_OFF);

    build_table<<<dim3(V_), dim3(256), 0, stream>>>(emb, W_ih, b_ih, b_hh, T2h);
    prepack<<<dim3(12), dim3(1024), 0, stream>>>(W_hh, Wpk);
    lstm_persistent<<<dim3(64), dim3(1024), 0, stream>>>(x, W_hh, T2h, Wpk, hlast);
    out_kernel<<<dim3(B_), dim3(O_), 0, stream>>>(hlast, W_out, b_out, out);
}

// Round 10
// 896.088 us; speedup vs baseline: 1.2972x; 1.2972x over previous
//
#include <hip/hip_runtime.h>

// CharNNClassifier: out = (LSTM(emb[x]) last h) @ W_out^T + b_out
// B=256 S=512 V=256 E=128 H=256 4H=1024 O=128, fp32 in/out.
//
// R12 = R10 with the Wpk stream software-pipelined (zero register delta).
//  R11 post-mortem: 3-kt stream = 3276 cyc/step of per-CU L2 delivery
//  (60 B/cyc/CU) > the 2484-cyc MFMA floor -> guaranteed regression
//  (measured +1182 ~= predicted +1092). Occupancy does NOT hide a shared
//  bandwidth floor. Law: resident W maximal, stream <= 2 kts, pipelined.
//  R10 residual (step 3881 vs floor 2484): wstr bursts issued at pass top
//  with ~930 cyc cover vs 1092 cyc delivery -> per-pass residual stalls,
//  plus epilogue tail + barrier.
//  R12: same 32-reg wstr window, loads moved for cover:
//   - pass1's frags loaded right AFTER pass0's MFMAs (cover = pass1 kt0-5)
//   - next step's pass0 frags loaded at step tail BEFORE __syncthreads
//     (cover = barrier + tcv + acc-init + kt0-5; barrier does not drain
//     loads-to-VGPR, waits land at first use)
//  Everything else identical to R10 (proven: 222 regs no spill, row-trick
//  epilogue, HSTRIDE 272, kt0..1 wlds / kt2..5 wreg / kt6..7 streamed).
//  Canary: WRITE_SIZE > 10 MB => compiler hoisted the loads (doubled
//  window) and spilled -> revert pipelining.

typedef _Float16 f16x8 __attribute__((ext_vector_type(8)));
typedef _Float16 f16x4 __attribute__((ext_vector_type(4)));
typedef float    f32x4 __attribute__((ext_vector_type(4)));

#define B_  256
#define S_  512
#define V_  256
#define E_  128
#define H_  256
#define O_  128

// ws layout (bytes)
#define T_OFF     0u              // T2h: 256*256*4 fp16 = 512 KiB
#define HLAST_OFF (512u << 10)    // hlast: 256*256*4B   = 256 KiB
#define WPK_OFF   (768u << 10)    // Wpk: 16*512*16B     = 128 KiB

// ---------------------------------------------------------------- K1: table
// T2h[v][unit] = fp16x4 {i,f,g,o} pre-activations from the embedding path.
__global__ void build_table(const float* __restrict__ emb,
                            const float* __restrict__ W_ih,
                            const float* __restrict__ b_ih,
                            const float* __restrict__ b_hh,
                            _Float16* __restrict__ T2h) {
    const int v   = blockIdx.x;   // vocab id
    const int tid = threadIdx.x;  // 256 threads = hidden unit

    __shared__ float e[E_];
    if (tid < E_) e[tid] = emb[v * E_ + tid];
    __syncthreads();

    f16x4 tv;
#pragma unroll
    for (int t = 0; t < 4; ++t) {
        const int g = t * 256 + tid;
        const float4* wp = (const float4*)(W_ih + g * E_);
        float acc = 0.f;
#pragma unroll
        for (int i = 0; i < E_ / 4; ++i) {
            float4 w = wp[i];
            acc += w.x * e[4*i] + w.y * e[4*i+1] + w.z * e[4*i+2] + w.w * e[4*i+3];
        }
        tv[t] = (_Float16)(acc + b_ih[g] + b_hh[g]);
    }
    *(f16x4*)(T2h + ((size_t)v * 256 + tid) * 4) = tv;
}

// ------------------------------------------------------- K1b: W-frag prepack
// Wpk[blk=ktS*8+j][tid] = the f16x8 B-fragment thread tid needs for
// (kt = 6+ktS, j). Lane math mirrors the main kernel's prologue.
__global__ void prepack(const float* __restrict__ W_hh,
                        _Float16* __restrict__ Wpk) {
    const int blk = blockIdx.x;      // 0..15 = ktS*8 + j
    const int ktS = blk >> 3;
    const int j   = blk & 7;
    const int kt  = 6 + ktS;
    const int tid = threadIdx.x;     // 512
    const int wv = tid >> 6, l = tid & 63, l15 = l & 15, quad = l >> 4;
    const int n  = j * 128 + wv * 16 + l15;   // gate column
    const int k0 = kt * 32 + quad * 8;
    const float4* wp = (const float4*)(W_hh + (size_t)n * H_ + k0);
    float4 w0 = wp[0];
    float4 w1 = wp[1];
    f16x8 f = (f16x8){
        (_Float16)w0.x, (_Float16)w0.y, (_Float16)w0.z, (_Float16)w0.w,
        (_Float16)w1.x, (_Float16)w1.y, (_Float16)w1.z, (_Float16)w1.w};
    *(f16x8*)(Wpk + ((size_t)blk * 512 + tid) * 8) = f;
}

// ------------------------------------------------------------ K2: recurrence
// Pre-act bounds: |W_hh row . h| <= 256*(1/16) = 16 hard; |table| < ~5.
// Sigmoid needs no clamp; tanh keeps a +-30 clamp as overflow insurance.
__device__ __forceinline__ float sig_fast(float x) {
    float t = __builtin_amdgcn_exp2f(-1.4426950408889634f * x);
    return __builtin_amdgcn_rcpf(1.f + t);
}
__device__ __forceinline__ float tanh_fast(float x) {
    x = fminf(fmaxf(x, -30.f), 30.f);
    float t = __builtin_amdgcn_exp2f(-2.8853900817779268f * x);  // e^{-2x}
    return (1.f - t) * __builtin_amdgcn_rcpf(1.f + t);
}

#define HSTRIDE 272   // fp16/row: 544 B => row bank-phase 0/8/16/24

__launch_bounds__(512, 2)
__global__ void lstm_persistent(const int* __restrict__ x,
                                const float* __restrict__ W_hh,
                                const _Float16* __restrict__ T2h,
                                const _Float16* __restrict__ Wpk,
                                float* __restrict__ hlast) {
    const int tid    = threadIdx.x;
    const int wv     = tid >> 6;     // wave 0..7
    const int l      = tid & 63;
    const int l15    = l & 15;
    const int quad   = l >> 4;       // 0..3  == this lane's batch row (local)
    const int stripe = blockIdx.x;   // batch rows [stripe*4, +4)
    const int uu     = wv * 16 + l15;    // unit (p=0 half)

    // LDS: 128 KB weights (kt 0..1) + 4-row h dbuf + zero block.
    __shared__ __align__(16) _Float16 wlds[8][8][2][512];   // 128 KiB
    __shared__ __align__(16) _Float16 hbuf[2][4][HSTRIDE];  // 4.25 KiB
    __shared__ __align__(16) _Float16 zbuf[256];            // 512 B zeros

    if (tid < 128) ((int*)zbuf)[tid] = 0;

    // ---- prologue: kt 0..5 of W_hh -> fp16 B-frags (kt 0..1 LDS, 2..5 reg)
    // col n = j*128 + wv*16 + l15; k = kt*32 + quad*8 + i; B[k][n] = W_hh[n][k]
    f16x8 wreg[8][4];
#pragma unroll
    for (int j = 0; j < 8; ++j) {
        const float* wr = W_hh + (size_t)(j * 128 + uu) * H_ + quad * 8;
#pragma unroll
        for (int kt = 0; kt < 6; ++kt) {
            const float4* wp = (const float4*)(wr + kt * 32);
            float4 w0 = wp[0];
            float4 w1 = wp[1];
            f16x8 f = (f16x8){
                (_Float16)w0.x, (_Float16)w0.y, (_Float16)w0.z, (_Float16)w0.w,
                (_Float16)w1.x, (_Float16)w1.y, (_Float16)w1.z, (_Float16)w1.w};
            if (kt < 2)
                *(f16x8*)&wlds[wv][j][kt][(size_t)l * 8] = f;
            else
                wreg[j][kt - 2] = f;
        }
    }

    const int grow = stripe * 4 + quad;   // this lane's global batch row
    float c2[2] = {0.f, 0.f};             // c[row=quad][uu], c[row=quad][uu+128]

    // x prefetch: 1 step ahead (one row per lane = quad).
    int xv = x[(size_t)grow * S_];

    // streamed kt6..7 window (32 regs), software-pipelined:
    //  - holds pass0 frags (j 0..3) across the step boundary
    //  - refilled with pass1 frags (j 4..7) right after pass0's MFMAs
    f16x8 wstr[4][2];

    __syncthreads();   // wlds + zbuf visible

    for (int s = 0; s < S_; ++s) {
        // T2h gather for THIS step (consumed in epilogue; MFMAs cover latency)
        f16x4 tcv[2];
        tcv[0] = *(const f16x4*)(T2h + ((size_t)xv * 256 + uu) * 4);
        tcv[1] = *(const f16x4*)(T2h + ((size_t)xv * 256 + uu + 128) * 4);
        if (s + 1 < S_) xv = x[(size_t)grow * S_ + s + 1];

        f32x4 acc[8];
#pragma unroll
        for (int j = 0; j < 8; ++j) acc[j] = (f32x4){0.f, 0.f, 0.f, 0.f};

        if (s > 0) {
            // A row m = l15; real rows m in {0,4,8,12} hold batch row m/4,
            // all other rows read the zero block. k = kt*32 + quad*8 + i.
            const _Float16* ha = ((l15 & 3) == 0)
                ? (&hbuf[(s - 1) & 1][l15 >> 2][0] + quad * 8)
                : (zbuf + quad * 8);

#pragma unroll
            for (int pass = 0; pass < 2; ++pass) {
#pragma unroll
                for (int kt = 0; kt < 8; ++kt) {
                    f16x8 a = *(const f16x8*)(ha + kt * 32);
                    if (kt < 2) {
#pragma unroll
                        for (int jj = 0; jj < 4; ++jj) {
                            f16x8 b = *(const f16x8*)
                                &wlds[wv][pass * 4 + jj][kt][(size_t)l * 8];
                            acc[pass * 4 + jj] =
                                __builtin_amdgcn_mfma_f32_16x16x32_f16(
                                    a, b, acc[pass * 4 + jj], 0, 0, 0);
                        }
                    } else if (kt < 6) {
#pragma unroll
                        for (int jj = 0; jj < 4; ++jj)
                            acc[pass * 4 + jj] =
                                __builtin_amdgcn_mfma_f32_16x16x32_f16(
                                    a, wreg[pass * 4 + jj][kt - 2],
                                    acc[pass * 4 + jj], 0, 0, 0);
                    } else {
#pragma unroll
                        for (int jj = 0; jj < 4; ++jj)
                            acc[pass * 4 + jj] =
                                __builtin_amdgcn_mfma_f32_16x16x32_f16(
                                    a, wstr[jj][kt - 6],
                                    acc[pass * 4 + jj], 0, 0, 0);
                    }
                }
                if (pass == 0) {
                    // refill window with pass1 frags (j 4..7); consumed at
                    // pass1 kt6 -> cover = pass1 kt0..5 MFMAs (~1200 cyc).
#pragma unroll
                    for (int jj = 0; jj < 4; ++jj)
#pragma unroll
                        for (int ktS = 0; ktS < 2; ++ktS)
                            wstr[jj][ktS] = *(const f16x8*)(
                                Wpk + ((size_t)((ktS * 8 + 4 + jj) * 512 + tid)) * 8);
                }
            }
        }

        // ---- epilogue straight from registers: gate t of unit half p is
        // acc[2t+p][0] (C row 4*quad = reg 0 of this lane).
        const bool last = (s == S_ - 1);
#pragma unroll
        for (int p = 0; p < 2; ++p) {
            float gi = sig_fast (acc[0 + p][0] + (float)tcv[p][0]);
            float gf = sig_fast (acc[2 + p][0] + (float)tcv[p][1]);
            float gg = tanh_fast(acc[4 + p][0] + (float)tcv[p][2]);
            float go = sig_fast (acc[6 + p][0] + (float)tcv[p][3]);
            float cc = gf * c2[p] + gi * gg;
            c2[p] = cc;
            float hv = go * tanh_fast(cc);
            if (!last) {
                hbuf[s & 1][quad][uu + p * 128] = (_Float16)hv;
            } else {
                hlast[(size_t)grow * H_ + uu + p * 128] = hv;
            }
        }

        // preload NEXT step's pass0 frags (j 0..3) BEFORE the barrier:
        // loads-to-VGPR are not drained by s_barrier; the wait lands at
        // next step's pass0 kt6 -> cover = barrier + tcv + init + kt0..5.
        if (!last) {
#pragma unroll
            for (int jj = 0; jj < 4; ++jj)
#pragma unroll
                for (int ktS = 0; ktS < 2; ++ktS)
                    wstr[jj][ktS] = *(const f16x8*)(
                        Wpk + ((size_t)((ktS * 8 + jj) * 512 + tid)) * 8);
        }

        // one barrier per step: h_s visible to all waves' A-reads at s+1;
        // buffer s&1 readers done before s+2 overwrites.
        __syncthreads();
    }
}

// ---------------------------------------------------------------- K3: head
__global__ void out_kernel(const float* __restrict__ hlast,
                           const float* __restrict__ W_out,
                           const float* __restrict__ b_out,
                           float* __restrict__ out) {
    const int b = blockIdx.x;    // 256
    const int o = threadIdx.x;   // 128
    __shared__ float hl[H_];
    hl[o]       = hlast[b * H_ + o];
    hl[o + 128] = hlast[b * H_ + o + 128];
    __syncthreads();
    const float4* wp = (const float4*)(W_out + o * H_);
    float acc = 0.f;
#pragma unroll
    for (int i = 0; i < H_ / 4; ++i) {
        float4 w = wp[i];
        acc += w.x * hl[4*i] + w.y * hl[4*i+1] + w.z * hl[4*i+2] + w.w * hl[4*i+3];
    }
    out[b * O_ + o] = acc + b_out[o];
}

// ----------------------------------------------------------------- launcher
extern "C" void kernel_launch(void* const* d_in, const int* in_sizes, int n_in,
                              void* d_out, int out_size, void* d_ws, size_t ws_size,
                              hipStream_t stream) {
    const int*   x     = (const int*)  d_in[0];
    const float* emb   = (const float*)d_in[1];
    const float* W_ih  = (const float*)d_in[2];
    const float* W_hh  = (const float*)d_in[3];
    const float* b_ih  = (const float*)d_in[4];
    const float* b_hh  = (const float*)d_in[5];
    const float* W_out = (const float*)d_in[6];
    const float* b_out = (const float*)d_in[7];
    float* out = (float*)d_out;

    char* ws = (char*)d_ws;
    _Float16* T2h   = (_Float16*)(ws + T_OFF);
    float*    hlast = (float*)(ws + HLAST_OFF);
    _Float16* Wpk   = (_Float16*)(ws + WPK_OFF);

    build_table<<<dim3(V_), dim3(256), 0, stream>>>(emb, W_ih, b_ih, b_hh, T2h);
    prepack<<<dim3(16), dim3(512), 0, stream>>>(W_hh, Wpk);
    lstm_persistent<<<dim3(64), dim3(512), 0, stream>>>(x, W_hh, T2h, Wpk, hlast);
    out_kernel<<<dim3(B_), dim3(O_), 0, stream>>>(hlast, W_out, b_out, out);
}

// Round 11
// 863.538 us; speedup vs baseline: 1.3461x; 1.0377x over previous
//
#include <hip/hip_runtime.h>

// CharNNClassifier: out = (LSTM(emb[x]) last h) @ W_out^T + b_out
// B=256 S=512 V=256 E=128 H=256 4H=1024 O=128, fp32 in/out.
//
// R13 = R12 with kt-split passes (A-fragment single-read).
//  R12 post-mortem: step 3765 cyc; LDS pipe ~2700-3200 cyc/CU-step is
//  co-binding with the 2484-cyc MFMA floor. Half the A-reads (16/wave)
//  exist only because passes split by j (pass1 re-reads all 8 A-frags).
//  R13: passes split by kt, streamed kts moved to {3,7} (one per half):
//   pass0 = kt0..3 (wlds,wlds,wreg,wstr) ; pass1 = kt4..7 (wreg x3,wstr).
//   - A-frags read ONCE each (8 ds_read_b128/wave/step, was 16): -768
//     LDS-pipe cyc/CU-step, conflicts ~halve.
//   - single 32-reg wstr window, refilled twice with ~900 cyc cover each:
//     kt3-window loaded at prev-step tail (across barrier, R12-proven);
//     kt7-window loaded right after kt3's MFMAs (cover kt4..6). One
//     sched_barrier(0) pins the refill below kt3 (bounds transient regs).
//   - register budget unchanged vs R12 (~215): acc32+wreg128+wstr32+misc.
//  Canary: WRITE_SIZE > 10 MB => spill => revert to R12.
//  W split: kt0,1 wlds (128 KB) | kt2,4,5,6 wreg (128 VGPR) | kt3,7 Wpk.
//  LDS = 128K wlds + 4.25K hbuf + 0.5K zbuf = 132.75 KB.

typedef _Float16 f16x8 __attribute__((ext_vector_type(8)));
typedef _Float16 f16x4 __attribute__((ext_vector_type(4)));
typedef float    f32x4 __attribute__((ext_vector_type(4)));

#define B_  256
#define S_  512
#define V_  256
#define E_  128
#define H_  256
#define O_  128

// ws layout (bytes)
#define T_OFF     0u              // T2h: 256*256*4 fp16 = 512 KiB
#define HLAST_OFF (512u << 10)    // hlast: 256*256*4B   = 256 KiB
#define WPK_OFF   (768u << 10)    // Wpk: 16*512*16B     = 128 KiB

// ---------------------------------------------------------------- K1: table
// T2h[v][unit] = fp16x4 {i,f,g,o} pre-activations from the embedding path.
__global__ void build_table(const float* __restrict__ emb,
                            const float* __restrict__ W_ih,
                            const float* __restrict__ b_ih,
                            const float* __restrict__ b_hh,
                            _Float16* __restrict__ T2h) {
    const int v   = blockIdx.x;   // vocab id
    const int tid = threadIdx.x;  // 256 threads = hidden unit

    __shared__ float e[E_];
    if (tid < E_) e[tid] = emb[v * E_ + tid];
    __syncthreads();

    f16x4 tv;
#pragma unroll
    for (int t = 0; t < 4; ++t) {
        const int g = t * 256 + tid;
        const float4* wp = (const float4*)(W_ih + g * E_);
        float acc = 0.f;
#pragma unroll
        for (int i = 0; i < E_ / 4; ++i) {
            float4 w = wp[i];
            acc += w.x * e[4*i] + w.y * e[4*i+1] + w.z * e[4*i+2] + w.w * e[4*i+3];
        }
        tv[t] = (_Float16)(acc + b_ih[g] + b_hh[g]);
    }
    *(f16x4*)(T2h + ((size_t)v * 256 + tid) * 4) = tv;
}

// ------------------------------------------------------- K1b: W-frag prepack
// Wpk[blk=ktS*8+j][tid] = the f16x8 B-fragment thread tid needs for
// (kt = 3 + ktS*4, j). Lane math mirrors the main kernel's prologue.
__global__ void prepack(const float* __restrict__ W_hh,
                        _Float16* __restrict__ Wpk) {
    const int blk = blockIdx.x;      // 0..15 = ktS*8 + j
    const int ktS = blk >> 3;        // 0 -> kt3, 1 -> kt7
    const int j   = blk & 7;
    const int kt  = 3 + ktS * 4;
    const int tid = threadIdx.x;     // 512
    const int wv = tid >> 6, l = tid & 63, l15 = l & 15, quad = l >> 4;
    const int n  = j * 128 + wv * 16 + l15;   // gate column
    const int k0 = kt * 32 + quad * 8;
    const float4* wp = (const float4*)(W_hh + (size_t)n * H_ + k0);
    float4 w0 = wp[0];
    float4 w1 = wp[1];
    f16x8 f = (f16x8){
        (_Float16)w0.x, (_Float16)w0.y, (_Float16)w0.z, (_Float16)w0.w,
        (_Float16)w1.x, (_Float16)w1.y, (_Float16)w1.z, (_Float16)w1.w};
    *(f16x8*)(Wpk + ((size_t)blk * 512 + tid) * 8) = f;
}

// ------------------------------------------------------------ K2: recurrence
// Pre-act bounds: |W_hh row . h| <= 256*(1/16) = 16 hard; |table| < ~5.
// Sigmoid needs no clamp; tanh keeps a +-30 clamp as overflow insurance.
__device__ __forceinline__ float sig_fast(float x) {
    float t = __builtin_amdgcn_exp2f(-1.4426950408889634f * x);
    return __builtin_amdgcn_rcpf(1.f + t);
}
__device__ __forceinline__ float tanh_fast(float x) {
    x = fminf(fmaxf(x, -30.f), 30.f);
    float t = __builtin_amdgcn_exp2f(-2.8853900817779268f * x);  // e^{-2x}
    return (1.f - t) * __builtin_amdgcn_rcpf(1.f + t);
}

#define HSTRIDE 272   // fp16/row: 544 B => row bank-phase 0/8/16/24

__launch_bounds__(512, 2)
__global__ void lstm_persistent(const int* __restrict__ x,
                                const float* __restrict__ W_hh,
                                const _Float16* __restrict__ T2h,
                                const _Float16* __restrict__ Wpk,
                                float* __restrict__ hlast) {
    const int tid    = threadIdx.x;
    const int wv     = tid >> 6;     // wave 0..7
    const int l      = tid & 63;
    const int l15    = l & 15;
    const int quad   = l >> 4;       // 0..3  == this lane's batch row (local)
    const int stripe = blockIdx.x;   // batch rows [stripe*4, +4)
    const int uu     = wv * 16 + l15;    // unit (p=0 half)

    // LDS: 128 KB weights (kt 0..1) + 4-row h dbuf + zero block.
    __shared__ __align__(16) _Float16 wlds[8][8][2][512];   // 128 KiB
    __shared__ __align__(16) _Float16 hbuf[2][4][HSTRIDE];  // 4.25 KiB
    __shared__ __align__(16) _Float16 zbuf[256];            // 512 B zeros

    if (tid < 128) ((int*)zbuf)[tid] = 0;

    // ---- prologue: kt {0,1}->wlds, {2,4,5,6}->wreg, {3,7} streamed later.
    // col n = j*128 + uu; k = kt*32 + quad*8 + i; B[k][n] = W_hh[n][k]
    f16x8 wreg[8][4];   // [j][m]: m=0->kt2, 1->kt4, 2->kt5, 3->kt6
#pragma unroll
    for (int j = 0; j < 8; ++j) {
        const float* wr = W_hh + (size_t)(j * 128 + uu) * H_ + quad * 8;
#pragma unroll
        for (int kt = 0; kt < 7; ++kt) {
            if (kt == 3) continue;   // streamed
            const float4* wp = (const float4*)(wr + kt * 32);
            float4 w0 = wp[0];
            float4 w1 = wp[1];
            f16x8 f = (f16x8){
                (_Float16)w0.x, (_Float16)w0.y, (_Float16)w0.z, (_Float16)w0.w,
                (_Float16)w1.x, (_Float16)w1.y, (_Float16)w1.z, (_Float16)w1.w};
            if (kt < 2)
                *(f16x8*)&wlds[wv][j][kt][(size_t)l * 8] = f;
            else
                wreg[j][(kt == 2) ? 0 : kt - 3] = f;
        }
    }

    const int grow = stripe * 4 + quad;   // this lane's global batch row
    float c2[2] = {0.f, 0.f};             // c[row=quad][uu], c[row=quad][uu+128]

    // x prefetch: 1 step ahead (one row per lane = quad).
    int xv = x[(size_t)grow * S_];

    // single streamed window (32 regs): holds kt3 frags across the step
    // boundary, refilled mid-step with kt7 frags.
    f16x8 wstr[8];
    const _Float16* wpk_lane = Wpk + (size_t)tid * 8;

    __syncthreads();   // wlds + zbuf visible

    for (int s = 0; s < S_; ++s) {
        // T2h gather for THIS step (consumed in epilogue; MFMAs cover latency)
        f16x4 tcv[2];
        tcv[0] = *(const f16x4*)(T2h + ((size_t)xv * 256 + uu) * 4);
        tcv[1] = *(const f16x4*)(T2h + ((size_t)xv * 256 + uu + 128) * 4);
        if (s + 1 < S_) xv = x[(size_t)grow * S_ + s + 1];

        f32x4 acc[8];
#pragma unroll
        for (int j = 0; j < 8; ++j) acc[j] = (f32x4){0.f, 0.f, 0.f, 0.f};

        if (s > 0) {
            // A row m = l15; real rows m in {0,4,8,12} hold batch row m/4,
            // all other rows read the zero block. k = kt*32 + quad*8 + i.
            const _Float16* ha = ((l15 & 3) == 0)
                ? (&hbuf[(s - 1) & 1][l15 >> 2][0] + quad * 8)
                : (zbuf + quad * 8);

            // ---- pass 0: kt 0..3, each A-frag read ONCE, all 8 j inner.
#pragma unroll
            for (int kt = 0; kt < 2; ++kt) {
                f16x8 a = *(const f16x8*)(ha + kt * 32);
#pragma unroll
                for (int j = 0; j < 8; ++j) {
                    f16x8 b = *(const f16x8*)&wlds[wv][j][kt][(size_t)l * 8];
                    acc[j] = __builtin_amdgcn_mfma_f32_16x16x32_f16(
                        a, b, acc[j], 0, 0, 0);
                }
            }
            {
                f16x8 a = *(const f16x8*)(ha + 2 * 32);
#pragma unroll
                for (int j = 0; j < 8; ++j)
                    acc[j] = __builtin_amdgcn_mfma_f32_16x16x32_f16(
                        a, wreg[j][0], acc[j], 0, 0, 0);
            }
            {
                f16x8 a = *(const f16x8*)(ha + 3 * 32);
#pragma unroll
                for (int j = 0; j < 8; ++j)
                    acc[j] = __builtin_amdgcn_mfma_f32_16x16x32_f16(
                        a, wstr[j], acc[j], 0, 0, 0);
            }

            // refill the window with kt7 frags; pin below kt3's MFMAs so
            // the old and new wstr live ranges don't overlap (reg bound).
            __builtin_amdgcn_sched_barrier(0);
#pragma unroll
            for (int j = 0; j < 8; ++j)
                wstr[j] = *(const f16x8*)(wpk_lane + ((size_t)(8 + j) * 512) * 8);

            // ---- pass 1: kt 4..6 resident, kt 7 streamed (cover = kt4..6).
#pragma unroll
            for (int m = 1; m < 4; ++m) {
                f16x8 a = *(const f16x8*)(ha + (m + 3) * 32);
#pragma unroll
                for (int j = 0; j < 8; ++j)
                    acc[j] = __builtin_amdgcn_mfma_f32_16x16x32_f16(
                        a, wreg[j][m], acc[j], 0, 0, 0);
            }
            {
                f16x8 a = *(const f16x8*)(ha + 7 * 32);
#pragma unroll
                for (int j = 0; j < 8; ++j)
                    acc[j] = __builtin_amdgcn_mfma_f32_16x16x32_f16(
                        a, wstr[j], acc[j], 0, 0, 0);
            }
        }

        // ---- epilogue straight from registers: gate t of unit half p is
        // acc[2t+p][0] (C row 4*quad = reg 0 of this lane).
        const bool last = (s == S_ - 1);
#pragma unroll
        for (int p = 0; p < 2; ++p) {
            float gi = sig_fast (acc[0 + p][0] + (float)tcv[p][0]);
            float gf = sig_fast (acc[2 + p][0] + (float)tcv[p][1]);
            float gg = tanh_fast(acc[4 + p][0] + (float)tcv[p][2]);
            float go = sig_fast (acc[6 + p][0] + (float)tcv[p][3]);
            float cc = gf * c2[p] + gi * gg;
            c2[p] = cc;
            float hv = go * tanh_fast(cc);
            if (!last) {
                hbuf[s & 1][quad][uu + p * 128] = (_Float16)hv;
            } else {
                hlast[(size_t)grow * H_ + uu + p * 128] = hv;
            }
        }

        // preload NEXT step's kt3 frags BEFORE the barrier (loads-to-VGPR
        // are not drained by s_barrier; wait lands at next step's kt3 ->
        // cover = barrier + tcv + init + kt0..2). R12-proven pattern.
        if (!last) {
#pragma unroll
            for (int j = 0; j < 8; ++j)
                wstr[j] = *(const f16x8*)(wpk_lane + ((size_t)j * 512) * 8);
        }

        // one barrier per step: h_s visible to all waves' A-reads at s+1;
        // buffer s&1 readers done before s+2 overwrites.
        __syncthreads();
    }
}

// ---------------------------------------------------------------- K3: head
__global__ void out_kernel(const float* __restrict__ hlast,
                           const float* __restrict__ W_out,
                           const float* __restrict__ b_out,
                           float* __restrict__ out) {
    const int b = blockIdx.x;    // 256
    const int o = threadIdx.x;   // 128
    __shared__ float hl[H_];
    hl[o]       = hlast[b * H_ + o];
    hl[o + 128] = hlast[b * H_ + o + 128];
    __syncthreads();
    const float4* wp = (const float4*)(W_out + o * H_);
    float acc = 0.f;
#pragma unroll
    for (int i = 0; i < H_ / 4; ++i) {
        float4 w = wp[i];
        acc += w.x * hl[4*i] + w.y * hl[4*i+1] + w.z * hl[4*i+2] + w.w * hl[4*i+3];
    }
    out[b * O_ + o] = acc + b_out[o];
}

// ----------------------------------------------------------------- launcher
extern "C" void kernel_launch(void* const* d_in, const int* in_sizes, int n_in,
                              void* d_out, int out_size, void* d_ws, size_t ws_size,
                              hipStream_t stream) {
    const int*   x     = (const int*)  d_in[0];
    const float* emb   = (const float*)d_in[1];
    const float* W_ih  = (const float*)d_in[2];
    const float* W_hh  = (const float*)d_in[3];
    const float* b_ih  = (const float*)d_in[4];
    const float* b_hh  = (const float*)d_in[5];
    const float* W_out = (const float*)d_in[6];
    const float* b_out = (const float*)d_in[7];
    float* out = (float*)d_out;

    char* ws = (char*)d_ws;
    _Float16* T2h   = (_Float16*)(ws + T_OFF);
    float*    hlast = (float*)(ws + HLAST_OFF);
    _Float16* Wpk   = (_Float16*)(ws + WPK_OFF);

    build_table<<<dim3(V_), dim3(256), 0, stream>>>(emb, W_ih, b_ih, b_hh, T2h);
    prepack<<<dim3(16), dim3(512), 0, stream>>>(W_hh, Wpk);
    lstm_persistent<<<dim3(64), dim3(512), 0, stream>>>(x, W_hh, T2h, Wpk, hlast);
    out_kernel<<<dim3(B_), dim3(O_), 0, stream>>>(hlast, W_out, b_out, out);
}